// Round 1
// baseline (902.661 us; speedup 1.0000x reference)
//
#include <hip/hip_runtime.h>
#include <hip/hip_bf16.h>
#include <stdint.h>

// Problem: B=8, T=2048, D=1024, E=8  -> M = B*T = 16384
// out[bt,o] = sum_e sigmoid( (x @ Wg[e]^T)[bt,o] + bg[e,o] ) * mix[bt,e]
// mix[bt,e] = a*topk_softmax_scatter + (1-a)*dense_softmax, a = sigmoid(alpha)
//
// Workspace layout (needs 48.5 MB):
//   [0, 512KB)           mix   f32 [16384][8]
//   [512KB, 512KB+32MB)  x_bf16  [16384][1024]
//   [+32MB, +48MB)       Wg_bf16 [8][1024][1024]

typedef __attribute__((ext_vector_type(4))) float f32x4;
typedef __attribute__((ext_vector_type(8))) short bf16x8;

#define BM 128
#define BN 128
#define BK 64

__device__ __forceinline__ unsigned short f2bf(float f) {
  unsigned u = __float_as_uint(f);
  u += 0x7fffu + ((u >> 16) & 1u);   // RNE
  return (unsigned short)(u >> 16);
}

__device__ __forceinline__ void gload_lds16(const void* g, void* l) {
  __builtin_amdgcn_global_load_lds(
      (const __attribute__((address_space(1))) void*)g,
      (__attribute__((address_space(3))) void*)l, 16, 0, 0);
}

// ---------------------------------------------------------------- cvt Wg ----
__global__ __launch_bounds__(256) void cvt_f32_to_bf16(
    const float4* __restrict__ src, ushort4* __restrict__ dst, int n4) {
  int i = blockIdx.x * 256 + threadIdx.x;
  int stride = gridDim.x * 256;
  for (; i < n4; i += stride) {
    float4 v = src[i];
    ushort4 o;
    o.x = f2bf(v.x); o.y = f2bf(v.y); o.z = f2bf(v.z); o.w = f2bf(v.w);
    dst[i] = o;
  }
}

// ------------------------------------------------- mix logits + x -> bf16 ----
// One wave per token (grid-stride over 16384 tokens). Wt/Wf staged in LDS.
__global__ __launch_bounds__(256) void mix_kernel(
    const float* __restrict__ x,      // [16384][1024]
    const float* __restrict__ Wf,     // [8][1024]
    const float* __restrict__ bfv,    // [8]
    const float* __restrict__ Wt,     // [8][1024]
    const float* __restrict__ btv,    // [8]
    const float* __restrict__ alpha,  // [1]
    const int* __restrict__ numk,     // [1]
    float* __restrict__ mixo,         // [16384][8]
    unsigned short* __restrict__ xb)  // [16384][1024] bf16 out
{
  __shared__ float wt_s[8 * 1024];  // 32 KB
  __shared__ float wf_s[8 * 1024];  // 32 KB
  for (int i = threadIdx.x; i < 8192; i += 256) {
    wt_s[i] = Wt[i];
    wf_s[i] = Wf[i];
  }
  __syncthreads();

  const int lane = threadIdx.x & 63;
  const int gw = blockIdx.x * 4 + (threadIdx.x >> 6);  // 0..1023
  const float aa = 1.f / (1.f + __expf(-alpha[0]));
  int k = numk[0]; k = k < 1 ? 1 : (k > 8 ? 8 : k);

  for (int t = gw; t < 16384; t += 1024) {
    const float4* xr = (const float4*)(x + (size_t)t * 1024);
    ushort4* xw = (ushort4*)(xb + (size_t)t * 1024);
    float accT[8], accF[8];
#pragma unroll
    for (int e = 0; e < 8; ++e) { accT[e] = 0.f; accF[e] = 0.f; }
#pragma unroll
    for (int c0 = 0; c0 < 4; ++c0) {
      int c = c0 * 64 + lane;
      float4 xv = xr[c];
      ushort4 o;
      o.x = f2bf(xv.x); o.y = f2bf(xv.y); o.z = f2bf(xv.z); o.w = f2bf(xv.w);
      xw[c] = o;
      int d = c * 4;
#pragma unroll
      for (int e = 0; e < 8; ++e) {
        float4 wt4 = *(const float4*)&wt_s[e * 1024 + d];
        float4 wf4 = *(const float4*)&wf_s[e * 1024 + d];
        accT[e] += xv.x * wt4.x + xv.y * wt4.y + xv.z * wt4.z + xv.w * wt4.w;
        accF[e] += xv.x * wf4.x + xv.y * wf4.y + xv.z * wf4.z + xv.w * wf4.w;
      }
    }
#pragma unroll
    for (int e = 0; e < 8; ++e) {
#pragma unroll
      for (int off = 32; off > 0; off >>= 1) {
        accT[e] += __shfl_xor(accT[e], off);
        accF[e] += __shfl_xor(accF[e], off);
      }
    }
    if (lane == 0) {
      float lt[8], lf[8];
#pragma unroll
      for (int e = 0; e < 8; ++e) { lt[e] = accT[e] + btv[e]; lf[e] = accF[e] + bfv[e]; }
      // dense softmax over feat logits
      float fm = lf[0];
#pragma unroll
      for (int e = 1; e < 8; ++e) fm = fmaxf(fm, lf[e]);
      float fs = 0.f;
#pragma unroll
      for (int e = 0; e < 8; ++e) { lf[e] = __expf(lf[e] - fm); fs += lf[e]; }
      float finv = 1.f / fs;
      // top-k (ties -> lowest index, matching lax.top_k)
      int usedmask = 0;
      float vsel[8]; int isel[8];
      for (int kk = 0; kk < k; ++kk) {
        float best = -3.4e38f; int bi = 0;
        for (int e = 0; e < 8; ++e) {
          if (!((usedmask >> e) & 1) && lt[e] > best) { best = lt[e]; bi = e; }
        }
        usedmask |= 1 << bi;
        vsel[kk] = best; isel[kk] = bi;
      }
      float tm = vsel[0], ts = 0.f;
      for (int kk = 0; kk < k; ++kk) { vsel[kk] = __expf(vsel[kk] - tm); ts += vsel[kk]; }
      float tinv = 1.f / ts;
      float* mo = mixo + (size_t)t * 8;
#pragma unroll
      for (int e = 0; e < 8; ++e) {
        float tp = 0.f;
        for (int kk = 0; kk < k; ++kk) if (isel[kk] == e) tp += vsel[kk] * tinv;
        mo[e] = aa * tp + (1.f - aa) * lf[e] * finv;
      }
    }
  }
}

// ------------------------------------------------------------ main GEMM ----
// Per block: 128x128 output tile, 4 waves (2x2), loop over 8 experts,
// K=1024 in 16 steps of BK=64, mfma_f32_16x16x32_bf16, fused sigmoid*mix.
__global__ __launch_bounds__(256, 1) void gate_gemm(
    const unsigned short* __restrict__ xb,   // [16384][1024] bf16
    const unsigned short* __restrict__ wgb,  // [8][1024][1024] bf16 (e, o, d)
    const float* __restrict__ bg,            // [8][1024]
    const float* __restrict__ mixv,          // [16384][8]
    float* __restrict__ out)                 // [16384][1024]
{
  __shared__ unsigned short As[BM * BK];  // 16 KB, [row][k] linear
  __shared__ unsigned short Bs[BN * BK];  // 16 KB, [o][k] linear
  __shared__ float mix_s[BM * 8];         // 4 KB  [row][e]
  __shared__ float bg_s[8 * BN];          // 4 KB  [e][col]

  const int tid = threadIdx.x;
  const int bm = blockIdx.x >> 3;
  const int bn = blockIdx.x & 7;
  const int row0 = bm * BM, col0 = bn * BN;

  for (int i = tid; i < BM * 8; i += 256) mix_s[i] = mixv[(size_t)row0 * 8 + i];
  for (int i = tid; i < 8 * BN; i += 256) {
    int e = i >> 7, c = i & 127;
    bg_s[i] = bg[e * 1024 + col0 + c];
  }

  const int wid = tid >> 6, lane = tid & 63;
  const int wr = wid >> 1, wc = wid & 1;
  const int m0 = wr * 64, n0 = wc * 64;
  const int fr = lane & 15, fq = lane >> 4;

  const f32x4 zero4 = {0.f, 0.f, 0.f, 0.f};
  f32x4 oacc[4][4];
#pragma unroll
  for (int i = 0; i < 4; ++i)
#pragma unroll
    for (int j = 0; j < 4; ++j) oacc[i][j] = zero4;

  for (int e = 0; e < 8; ++e) {
    const unsigned short* wge = wgb + ((size_t)e << 20);
    f32x4 acc[4][4];
#pragma unroll
    for (int i = 0; i < 4; ++i)
#pragma unroll
      for (int j = 0; j < 4; ++j) acc[i][j] = zero4;

    for (int kt = 0; kt < 16; ++kt) {
      const int k0 = kt * BK;
      __syncthreads();  // previous tile fully consumed
#pragma unroll
      for (int i = 0; i < 4; ++i) {
        const int cbase = (wid * 4 + i) * 64;  // 16B-chunk base for this wave-call
        const int c = cbase + lane;
        const int r = c >> 3;            // tile row (8 chunks of 8 bf16 per 64-wide row)
        const int kc = (c & 7) * 8;      // k offset within row
        gload_lds16(xb + (size_t)(row0 + r) * 1024 + k0 + kc, &As[cbase * 8]);
        gload_lds16(wge + (size_t)(col0 + r) * 1024 + k0 + kc, &Bs[cbase * 8]);
      }
      __syncthreads();  // staged (compiler drains vmcnt before barrier)
#pragma unroll
      for (int ks = 0; ks < 2; ++ks) {
        bf16x8 af[4], bfr[4];
#pragma unroll
        for (int i = 0; i < 4; ++i)
          af[i] = *(const bf16x8*)&As[(m0 + i * 16 + fr) * BK + ks * 32 + fq * 8];
#pragma unroll
        for (int j = 0; j < 4; ++j)
          bfr[j] = *(const bf16x8*)&Bs[(n0 + j * 16 + fr) * BK + ks * 32 + fq * 8];
#pragma unroll
        for (int i = 0; i < 4; ++i)
#pragma unroll
          for (int j = 0; j < 4; ++j)
            acc[i][j] = __builtin_amdgcn_mfma_f32_16x16x32_bf16(af[i], bfr[j], acc[i][j], 0, 0, 0);
      }
    }

    // epilogue: oacc += sigmoid(acc + bg[e,col]) * mix[row,e]
    float mrow[4][4];
#pragma unroll
    for (int i = 0; i < 4; ++i)
#pragma unroll
      for (int r = 0; r < 4; ++r)
        mrow[i][r] = mix_s[(m0 + i * 16 + fq * 4 + r) * 8 + e];
    float bgj[4];
#pragma unroll
    for (int j = 0; j < 4; ++j) bgj[j] = bg_s[e * BN + n0 + j * 16 + fr];
#pragma unroll
    for (int i = 0; i < 4; ++i)
#pragma unroll
      for (int j = 0; j < 4; ++j)
#pragma unroll
        for (int r = 0; r < 4; ++r) {
          float v = acc[i][j][r] + bgj[j];
          float s = __builtin_amdgcn_rcpf(1.f + __expf(-v));
          oacc[i][j][r] += s * mrow[i][r];
        }
  }

  // store C: row = row0+m0+i*16+fq*4+r, col = col0+n0+j*16+fr
#pragma unroll
  for (int i = 0; i < 4; ++i)
#pragma unroll
    for (int r = 0; r < 4; ++r) {
      const int row = row0 + m0 + i * 16 + fq * 4 + r;
      float* orow = out + (size_t)row * 1024 + col0 + n0 + fr;
#pragma unroll
      for (int j = 0; j < 4; ++j) orow[j * 16] = oacc[i][j][r];
    }
}

// ---------------------------------------------------------------- launch ----
extern "C" void kernel_launch(void* const* d_in, const int* in_sizes, int n_in,
                              void* d_out, int out_size, void* d_ws, size_t ws_size,
                              hipStream_t stream) {
  const float* x     = (const float*)d_in[0];
  const float* Wg    = (const float*)d_in[1];
  const float* bg    = (const float*)d_in[2];
  const float* Wf    = (const float*)d_in[3];
  const float* bfv   = (const float*)d_in[4];
  const float* Wt    = (const float*)d_in[5];
  const float* btv   = (const float*)d_in[6];
  const float* alpha = (const float*)d_in[7];
  const int*   num   = (const int*)d_in[8];
  float* out = (float*)d_out;

  char* ws = (char*)d_ws;
  float* mixbuf = (float*)ws;                                      // 512 KB
  unsigned short* xb  = (unsigned short*)(ws + (1u << 19));        // 32 MB
  unsigned short* wgb = (unsigned short*)(ws + (1u << 19) + (32u << 20));  // 16 MB

  cvt_f32_to_bf16<<<dim3(1024), dim3(256), 0, stream>>>(
      (const float4*)Wg, (ushort4*)wgb, (8 * 1024 * 1024) / 4);
  mix_kernel<<<dim3(256), dim3(256), 0, stream>>>(
      x, Wf, bfv, Wt, btv, alpha, num, mixbuf, xb);
  gate_gemm<<<dim3(1024), dim3(256), 0, stream>>>(xb, wgb, bg, mixbuf, out);
}

// Round 2
// 582.450 us; speedup vs baseline: 1.5498x; 1.5498x over previous
//
#include <hip/hip_runtime.h>
#include <hip/hip_bf16.h>
#include <stdint.h>

// Problem: B=8, T=2048, D=1024, E=8  -> M = B*T = 16384
// out[bt,o] = sum_e sigmoid( (x @ Wg[e]^T)[bt,o] + bg[e,o] ) * mix[bt,e]
// mix[bt,e] = a*topk_softmax_scatter + (1-a)*dense_softmax, a = sigmoid(alpha)
//
// Workspace layout (needs 48.5 MB):
//   [0, 512KB)           mix   f32 [16384][8]
//   [512KB, 512KB+32MB)  x_bf16  [16384][1024]
//   [+32MB, +48MB)       Wg_bf16 [8][1024][1024]

typedef __attribute__((ext_vector_type(4))) float f32x4;
typedef __attribute__((ext_vector_type(8))) short bf16x8;

#define BM 128
#define BN 128
#define BK 64

__device__ __forceinline__ unsigned short f2bf(float f) {
  unsigned u = __float_as_uint(f);
  u += 0x7fffu + ((u >> 16) & 1u);   // RNE
  return (unsigned short)(u >> 16);
}

__device__ __forceinline__ void gload_lds16(const void* g, void* l) {
  __builtin_amdgcn_global_load_lds(
      (const __attribute__((address_space(1))) void*)g,
      (__attribute__((address_space(3))) void*)l, 16, 0, 0);
}

// ---------------------------------------------------------------- cvt Wg ----
__global__ __launch_bounds__(256) void cvt_f32_to_bf16(
    const float4* __restrict__ src, ushort4* __restrict__ dst, int n4) {
  int i = blockIdx.x * 256 + threadIdx.x;
  int stride = gridDim.x * 256;
  for (; i < n4; i += stride) {
    float4 v = src[i];
    ushort4 o;
    o.x = f2bf(v.x); o.y = f2bf(v.y); o.z = f2bf(v.z); o.w = f2bf(v.w);
    dst[i] = o;
  }
}

// ------------------------------------------------- mix logits + x -> bf16 ----
// One wave per token (8192 waves, 2 tokens each). Wt/Wf staged in LDS.
__global__ __launch_bounds__(256) void mix_kernel(
    const float* __restrict__ x,      // [16384][1024]
    const float* __restrict__ Wf,     // [8][1024]
    const float* __restrict__ bfv,    // [8]
    const float* __restrict__ Wt,     // [8][1024]
    const float* __restrict__ btv,    // [8]
    const float* __restrict__ alpha,  // [1]
    const int* __restrict__ numk,     // [1]
    float* __restrict__ mixo,         // [16384][8]
    unsigned short* __restrict__ xb)  // [16384][1024] bf16 out
{
  __shared__ float wt_s[8 * 1024];  // 32 KB
  __shared__ float wf_s[8 * 1024];  // 32 KB
  for (int i = threadIdx.x; i < 8192; i += 256) {
    wt_s[i] = Wt[i];
    wf_s[i] = Wf[i];
  }
  __syncthreads();

  const int lane = threadIdx.x & 63;
  const int gw = blockIdx.x * 4 + (threadIdx.x >> 6);  // 0..8191
  const float aa = 1.f / (1.f + __expf(-alpha[0]));
  int k = numk[0]; k = k < 1 ? 1 : (k > 8 ? 8 : k);

  for (int t = gw; t < 16384; t += 8192) {
    const float4* xr = (const float4*)(x + (size_t)t * 1024);
    ushort4* xw = (ushort4*)(xb + (size_t)t * 1024);
    float accT[8], accF[8];
#pragma unroll
    for (int e = 0; e < 8; ++e) { accT[e] = 0.f; accF[e] = 0.f; }
#pragma unroll
    for (int c0 = 0; c0 < 4; ++c0) {
      int c = c0 * 64 + lane;
      float4 xv = xr[c];
      ushort4 o;
      o.x = f2bf(xv.x); o.y = f2bf(xv.y); o.z = f2bf(xv.z); o.w = f2bf(xv.w);
      xw[c] = o;
      int d = c * 4;
#pragma unroll
      for (int e = 0; e < 8; ++e) {
        float4 wt4 = *(const float4*)&wt_s[e * 1024 + d];
        float4 wf4 = *(const float4*)&wf_s[e * 1024 + d];
        accT[e] += xv.x * wt4.x + xv.y * wt4.y + xv.z * wt4.z + xv.w * wt4.w;
        accF[e] += xv.x * wf4.x + xv.y * wf4.y + xv.z * wf4.z + xv.w * wf4.w;
      }
    }
#pragma unroll
    for (int e = 0; e < 8; ++e) {
#pragma unroll
      for (int off = 32; off > 0; off >>= 1) {
        accT[e] += __shfl_xor(accT[e], off);
        accF[e] += __shfl_xor(accF[e], off);
      }
    }
    if (lane == 0) {
      float lt[8], lf[8];
#pragma unroll
      for (int e = 0; e < 8; ++e) { lt[e] = accT[e] + btv[e]; lf[e] = accF[e] + bfv[e]; }
      float fm = lf[0];
#pragma unroll
      for (int e = 1; e < 8; ++e) fm = fmaxf(fm, lf[e]);
      float fs = 0.f;
#pragma unroll
      for (int e = 0; e < 8; ++e) { lf[e] = __expf(lf[e] - fm); fs += lf[e]; }
      float finv = 1.f / fs;
      // top-k (ties -> lowest index, matching lax.top_k)
      int usedmask = 0;
      float vsel[8]; int isel[8];
      for (int kk = 0; kk < k; ++kk) {
        float best = -3.4e38f; int bi = 0;
        for (int e = 0; e < 8; ++e) {
          if (!((usedmask >> e) & 1) && lt[e] > best) { best = lt[e]; bi = e; }
        }
        usedmask |= 1 << bi;
        vsel[kk] = best; isel[kk] = bi;
      }
      float tm = vsel[0], ts = 0.f;
      for (int kk = 0; kk < k; ++kk) { vsel[kk] = __expf(vsel[kk] - tm); ts += vsel[kk]; }
      float tinv = 1.f / ts;
      float* mo = mixo + (size_t)t * 8;
#pragma unroll
      for (int e = 0; e < 8; ++e) {
        float tp = 0.f;
        for (int kk = 0; kk < k; ++kk) if (isel[kk] == e) tp += vsel[kk] * tinv;
        mo[e] = aa * tp + (1.f - aa) * lf[e] * finv;
      }
    }
  }
}

// ------------------------------------------------------------ main GEMM ----
// 128x128 tile, 4 waves (2x2), flattened (expert x ktile) pipeline:
// 2-phase dbuf — stage(next) issued BEFORE compute(cur), single barrier/step.
// LDS XOR-swizzle (rule 21): linear dest via global_load_lds, inverse-swizzled
// global source, swizzled ds_read. chunk c holds (row=c>>3, k8=(c&7)^(row&7)).
__global__ __launch_bounds__(256, 2) void gate_gemm(
    const unsigned short* __restrict__ xb,   // [16384][1024] bf16
    const unsigned short* __restrict__ wgb,  // [8][1024][1024] bf16 (e, o, d)
    const float* __restrict__ bg,            // [8][1024]
    const float* __restrict__ mixv,          // [16384][8]
    float* __restrict__ out)                 // [16384][1024]
{
  __shared__ unsigned short As[2][BM * BK];  // 2 x 16 KB
  __shared__ unsigned short Bs[2][BN * BK];  // 2 x 16 KB
  __shared__ float mix_s[BM * 8];            // 4 KB  [row][e]
  __shared__ float bg_s[8 * BN];             // 4 KB  [e][col]

  const int tid = threadIdx.x;
  const int bm = blockIdx.x >> 3;
  const int bn = blockIdx.x & 7;
  const int row0 = bm * BM, col0 = bn * BN;

  for (int i = tid; i < BM * 8; i += 256) mix_s[i] = mixv[(size_t)row0 * 8 + i];
  for (int i = tid; i < 8 * BN; i += 256) {
    int e = i >> 7, c = i & 127;
    bg_s[i] = bg[e * 1024 + col0 + c];
  }

  const int wid = tid >> 6, lane = tid & 63;
  const int wr = wid >> 1, wc = wid & 1;
  const int m0 = wr * 64, n0 = wc * 64;
  const int fr = lane & 15, fq = lane >> 4;

  const unsigned short* aBase = xb + (size_t)row0 * 1024;
  const unsigned short* bBase = wgb + (size_t)col0 * 1024;

  // per-lane staging geometry (4 chunks each for A and B)
  int st_row[4], st_off[4], st_dst[4];
#pragma unroll
  for (int i = 0; i < 4; ++i) {
    const int cbase = (wid * 4 + i) * 64;
    const int c = cbase + lane;
    const int row = c >> 3;
    const int k8 = (c & 7) ^ (row & 7);   // inverse swizzle on the SOURCE
    st_row[i] = row;
    st_off[i] = row * 1024 + k8 * 8;
    st_dst[i] = cbase * 8;                // linear LDS dest (ushort units)
  }

#define STAGE(buf, koff, ebase)                                        \
  {                                                                     \
    _Pragma("unroll")                                                   \
    for (int i = 0; i < 4; ++i) {                                       \
      gload_lds16(aBase + (size_t)(koff) + st_off[i], &As[buf][st_dst[i]]); \
      gload_lds16(bBase + (ebase) + (size_t)(koff) + st_off[i], &Bs[buf][st_dst[i]]); \
    }                                                                   \
  }

  const f32x4 zero4 = {0.f, 0.f, 0.f, 0.f};
  f32x4 oacc[4][4], acc[4][4];
#pragma unroll
  for (int i = 0; i < 4; ++i)
#pragma unroll
    for (int j = 0; j < 4; ++j) { oacc[i][j] = zero4; acc[i][j] = zero4; }

  // fragment LDS indices (ushort): (row*64 + (ks*4+fq)^(fr&7) * 8), row=m/n0+i*16+fr
  int ka0 = ((0 * 4 + fq) ^ (fr & 7)) * 8;
  int ka1 = ((1 * 4 + fq) ^ (fr & 7)) * 8;

  STAGE(0, 0, 0);
  __syncthreads();

  int cur = 0;
  for (int it = 0; it < 128; ++it) {
    const int e = it >> 4, kt = it & 15;
    if (it < 127) {
      const int nit = it + 1;
      const size_t nebase = (size_t)(nit >> 4) << 20;
      const int nkoff = (nit & 15) * 64;
      STAGE(cur ^ 1, nkoff, nebase);
    }
    const unsigned short* sA = As[cur];
    const unsigned short* sB = Bs[cur];
#pragma unroll
    for (int ks = 0; ks < 2; ++ks) {
      const int kx = ks ? ka1 : ka0;
      bf16x8 af[4], bfr[4];
#pragma unroll
      for (int i = 0; i < 4; ++i)
        af[i] = *(const bf16x8*)&sA[(m0 + i * 16 + fr) * BK + kx];
#pragma unroll
      for (int j = 0; j < 4; ++j)
        bfr[j] = *(const bf16x8*)&sB[(n0 + j * 16 + fr) * BK + kx];
#pragma unroll
      for (int i = 0; i < 4; ++i)
#pragma unroll
        for (int j = 0; j < 4; ++j)
          acc[i][j] = __builtin_amdgcn_mfma_f32_16x16x32_bf16(af[i], bfr[j], acc[i][j], 0, 0, 0);
    }

    if (kt == 15) {
      // epilogue: oacc += sigmoid(acc + bg[e,col]) * mix[row,e]; reset acc
      float mrow[4][4];
#pragma unroll
      for (int i = 0; i < 4; ++i)
#pragma unroll
        for (int r = 0; r < 4; ++r)
          mrow[i][r] = mix_s[(m0 + i * 16 + fq * 4 + r) * 8 + e];
      float bgj[4];
#pragma unroll
      for (int j = 0; j < 4; ++j) bgj[j] = bg_s[e * BN + n0 + j * 16 + fr];
#pragma unroll
      for (int i = 0; i < 4; ++i)
#pragma unroll
        for (int j = 0; j < 4; ++j)
#pragma unroll
          for (int r = 0; r < 4; ++r) {
            float v = acc[i][j][r] + bgj[j];
            float s = __builtin_amdgcn_rcpf(1.f + __expf(-v));
            oacc[i][j][r] += s * mrow[i][r];
            acc[i][j][r] = 0.f;
          }
    }
    __syncthreads();
    cur ^= 1;
  }

  // store C: row = row0+m0+i*16+fq*4+r, col = col0+n0+j*16+fr
#pragma unroll
  for (int i = 0; i < 4; ++i)
#pragma unroll
    for (int r = 0; r < 4; ++r) {
      const int row = row0 + m0 + i * 16 + fq * 4 + r;
      float* orow = out + (size_t)row * 1024 + col0 + n0 + fr;
#pragma unroll
      for (int j = 0; j < 4; ++j) orow[j * 16] = oacc[i][j][r];
    }
#undef STAGE
}

// ---------------------------------------------------------------- launch ----
extern "C" void kernel_launch(void* const* d_in, const int* in_sizes, int n_in,
                              void* d_out, int out_size, void* d_ws, size_t ws_size,
                              hipStream_t stream) {
  const float* x     = (const float*)d_in[0];
  const float* Wg    = (const float*)d_in[1];
  const float* bg    = (const float*)d_in[2];
  const float* Wf    = (const float*)d_in[3];
  const float* bfv   = (const float*)d_in[4];
  const float* Wt    = (const float*)d_in[5];
  const float* btv   = (const float*)d_in[6];
  const float* alpha = (const float*)d_in[7];
  const int*   num   = (const int*)d_in[8];
  float* out = (float*)d_out;

  char* ws = (char*)d_ws;
  float* mixbuf = (float*)ws;                                      // 512 KB
  unsigned short* xb  = (unsigned short*)(ws + (1u << 19));        // 32 MB
  unsigned short* wgb = (unsigned short*)(ws + (1u << 19) + (32u << 20));  // 16 MB

  cvt_f32_to_bf16<<<dim3(2048), dim3(256), 0, stream>>>(
      (const float4*)Wg, (ushort4*)wgb, (8 * 1024 * 1024) / 4);
  mix_kernel<<<dim3(2048), dim3(256), 0, stream>>>(
      x, Wf, bfv, Wt, btv, alpha, num, mixbuf, xb);
  gate_gemm<<<dim3(1024), dim3(256), 0, stream>>>(xb, wgb, bg, mixbuf, out);
}